// Round 1
// baseline (248.103 us; speedup 1.0000x reference)
//
#include <hip/hip_runtime.h>
#include <hip/hip_bf16.h>
#include <math.h>

// Problem constants
#define Bq  2
#define Sq  2048
#define Hq  1024
#define Nq  16
#define HNq 64
#define Mq  (Bq*Sq)        // 4096 rows
#define H3q (3*Hq)         // 3072

#define LOG2E 1.44269504088896340736f

typedef __attribute__((ext_vector_type(8))) short           short8;
typedef __attribute__((ext_vector_type(4))) short           short4s;
typedef __attribute__((ext_vector_type(8))) unsigned short  ushortx8;
typedef __attribute__((ext_vector_type(4))) unsigned short  ushortx4;
typedef __attribute__((ext_vector_type(4))) float           floatx4;

__device__ __forceinline__ unsigned short f2bf(float f) {
    union { float f; unsigned int u; } x; x.f = f;
    unsigned int r = (x.u + 0x7fffu + ((x.u >> 16) & 1u)) >> 16;
    return (unsigned short)r;
}

// packed fp32x2 -> bf16x2 (v_cvt_pk_bf16_f32 on gfx950); a in low 16 bits
__device__ __forceinline__ unsigned int pkbf(float a, float b) {
    float2 t; t.x = a; t.y = b;
    __hip_bfloat162 h = __float22bfloat162_rn(t);
    union { __hip_bfloat162 h; unsigned int u; } c; c.h = h;
    return c.u;
}

__device__ __forceinline__ float bf2f(unsigned short v) {
    union { unsigned int u; float f; } x; x.u = (unsigned int)v << 16;
    return x.f;
}

// async global->LDS, 16B per lane; LDS dest = wave-uniform base + lane*16
__device__ __forceinline__ void gload16(const unsigned short* g, unsigned short* l) {
    __builtin_amdgcn_global_load_lds(
        (__attribute__((address_space(1))) void*)(unsigned long long)(g),
        (__attribute__((address_space(3))) void*)(unsigned int)(unsigned long long)(l),
        16, 0, 0);
}

// LDS bank swizzle: granule' = granule ^ swz(row mod 16); 2-way max conflict
__device__ __forceinline__ int swz(int r) { return (r ^ (r >> 2)) & 3; }

// ---------------------------------------------------------------------------
// Fused fp32 -> bf16 cast for hidden | W_qkv | W_out (contiguous bf16 dst)
// ---------------------------------------------------------------------------
#define N_HID ((size_t)Mq * Hq)          // 4194304
#define N_HW  (N_HID + (size_t)H3q * Hq) // 7340032
#define N_ALL (N_HW + (size_t)Hq * Hq)   // 8388608

__global__ __launch_bounds__(256) void cvt_all(
    const float* __restrict__ hidden, const float* __restrict__ wqkv,
    const float* __restrict__ wout, unsigned short* __restrict__ dst)
{
    size_t i = ((size_t)blockIdx.x * 256 + threadIdx.x) * 8;
    const float* src;
    if (i < N_HID)      src = hidden + i;
    else if (i < N_HW)  src = wqkv + (i - N_HID);
    else                src = wout + (i - N_HW);
    float4 a = *(const float4*)(src);
    float4 b = *(const float4*)(src + 4);
    union { unsigned int u[4]; ushortx8 s; } o;
    o.u[0] = pkbf(a.x, a.y); o.u[1] = pkbf(a.z, a.w);
    o.u[2] = pkbf(b.x, b.y); o.u[3] = pkbf(b.z, b.w);
    *(ushortx8*)(dst + i) = o.s;
}

// expmask[i] = 2^(mask[i]*log2e) = e^mask, bf16. 4096 elems, 2 blocks.
__global__ __launch_bounds__(256) void cvt_mask(
    const float* __restrict__ mask, unsigned short* __restrict__ em)
{
    int i = (blockIdx.x * 256 + threadIdx.x) * 8;
    union { unsigned int u[4]; ushortx8 s; } o;
    #pragma unroll
    for (int h = 0; h < 4; h++) {
        float a = exp2f(mask[i + 2*h]     * LOG2E);
        float b = exp2f(mask[i + 2*h + 1] * LOG2E);
        o.u[h] = pkbf(a, b);
    }
    *(ushortx8*)(em + i) = o.s;
}

// ---------------------------------------------------------------------------
// MFMA GEMM core: 128x128 tile, BK=32, 4 waves each computing 64x64.
// ---------------------------------------------------------------------------
#define TM 128
#define TN 128
#define TK 32

// GEMM1: QKV projection. Outputs split into three dedicated buffers:
//   Qb [row][1024]  Q * 0.125*log2e (bf16)
//   Kd [row][1024]  K (bf16), dense rows for contiguous global_load_lds
//   V5 [b][n][ktile32][kg16][l15 16][dt4][r4]  V'^T fragment-packed with
//       e^mask folded in, so attention's PV fragments are direct coalesced
//       16B global loads (no LDS round-trip).
__global__ __launch_bounds__(256) void gemm_mfma_qkv(
    const unsigned short* __restrict__ A, const unsigned short* __restrict__ Bw,
    const float* __restrict__ bias, const float* __restrict__ mask,
    unsigned short* __restrict__ Qb, unsigned short* __restrict__ Kd,
    unsigned short* __restrict__ V5, int K)
{
    __shared__ unsigned short As[TM][TK];
    __shared__ unsigned short Bs[TN][TK];

    const int tid = threadIdx.x;
    const int w = tid >> 6, lane = tid & 63;
    const int l15 = lane & 15, quad = lane >> 4;
    const int wr = (w & 1) * 64;
    const int wc = (w >> 1) * 64;
    const int row0 = blockIdx.y * TM;
    const int col0 = blockIdx.x * TN;

    const int srow16 = lane >> 2;
    const int sgd    = lane & 3;
    const int sgsrc  = (sgd ^ swz(srow16)) * 8;

    floatx4 acc[4][4];
    #pragma unroll
    for (int i = 0; i < 4; i++)
        #pragma unroll
        for (int j = 0; j < 4; j++) acc[i][j] = (floatx4){0.f,0.f,0.f,0.f};

    const int aswz = swz(l15) * 8;

    for (int k0 = 0; k0 < K; k0 += TK) {
        __syncthreads();
        #pragma unroll
        for (int c = 0; c < 2; c++) {
            int seg = w * 2 + c;
            int r = seg * 16 + srow16;
            gload16(A  + (size_t)(row0 + r) * K + k0 + sgsrc, &As[seg * 16][0]);
            gload16(Bw + (size_t)(col0 + r) * K + k0 + sgsrc, &Bs[seg * 16][0]);
        }
        __syncthreads();

        short8 af[4], bf[4];
        #pragma unroll
        for (int i = 0; i < 4; i++)
            af[i] = *(const short8*)&As[wr + i * 16 + l15][(quad * 8) ^ aswz];
        #pragma unroll
        for (int j = 0; j < 4; j++)
            bf[j] = *(const short8*)&Bs[wc + j * 16 + l15][(quad * 8) ^ aswz];
        #pragma unroll
        for (int i = 0; i < 4; i++)
            #pragma unroll
            for (int j = 0; j < 4; j++)
                acc[i][j] = __builtin_amdgcn_mfma_f32_16x16x32_bf16(af[i], bf[j], acc[i][j], 0, 0, 0);
    }

    const int cls = col0 >> 10;    // 0=Q, 1=K, 2=V; uniform per block (128|1024)

    if (cls == 2) {
        #pragma unroll
        for (int i = 0; i < 4; i++) {
            const int rb = row0 + wr + i * 16 + quad * 4;
            const int b  = rb >> 11;
            const int s  = rb & (Sq - 1);
            float expm[4];
            #pragma unroll
            for (int rr = 0; rr < 4; rr++)
                expm[rr] = exp2f(mask[(size_t)b * Sq + s + rr] * LOG2E);
            #pragma unroll
            for (int j = 0; j < 4; j++) {
                const int c  = col0 + wc + j * 16 + l15;
                const int c2 = c - 2 * Hq;           // n*64+d
                const int n  = c2 >> 6, d = c2 & 63;
                const float bia = bias[c];
                ushortx4 o;
                #pragma unroll
                for (int rr = 0; rr < 4; rr++)
                    o[rr] = f2bf((acc[i][j][rr] + bia) * expm[rr]);
                const size_t off = ((((size_t)(b * Nq + n)) * 32 + (s >> 6)) << 12)
                                 + (size_t)((((s >> 2) & 15) << 8) + ((d & 15) << 4) + ((d >> 4) << 2));
                *(ushortx4*)&V5[off] = o;
            }
        }
    } else {
        unsigned short* __restrict__ dst = (cls == 0) ? Qb : Kd;
        const int cshift = (cls == 0) ? 0 : Hq;
        const float qs = (cls == 0) ? (0.125f * LOG2E) : 1.0f;
        #pragma unroll
        for (int i = 0; i < 4; i++) {
            const int rb = row0 + wr + i * 16 + quad * 4;
            #pragma unroll
            for (int j = 0; j < 4; j++) {
                const int c = col0 + wc + j * 16 + l15;
                const float bia = bias[c];
                #pragma unroll
                for (int rr = 0; rr < 4; rr++)
                    dst[(size_t)(rb + rr) * Hq + (c - cshift)] =
                        f2bf((acc[i][j][rr] + bia) * qs);
            }
        }
    }
}

// GEMM2: x = A*Bw^T + bias + residual -> bf16 (LN reads bf16, stats in fp32)
__global__ __launch_bounds__(256) void gemm_mfma_out(
    const unsigned short* __restrict__ A, const unsigned short* __restrict__ Bw,
    const float* __restrict__ bias, const float* __restrict__ res,
    unsigned short* __restrict__ X, int M, int Nd, int K)
{
    __shared__ unsigned short As[TM][TK];
    __shared__ unsigned short Bs[TN][TK];

    const int tid = threadIdx.x;
    const int w = tid >> 6, lane = tid & 63;
    const int l15 = lane & 15, quad = lane >> 4;
    const int wr = (w & 1) * 64;
    const int wc = (w >> 1) * 64;
    const int row0 = blockIdx.y * TM;
    const int col0 = blockIdx.x * TN;

    const int srow16 = lane >> 2;
    const int sgd    = lane & 3;
    const int sgsrc  = (sgd ^ swz(srow16)) * 8;

    floatx4 acc[4][4];
    #pragma unroll
    for (int i = 0; i < 4; i++)
        #pragma unroll
        for (int j = 0; j < 4; j++) acc[i][j] = (floatx4){0.f,0.f,0.f,0.f};

    const int aswz = swz(l15) * 8;

    for (int k0 = 0; k0 < K; k0 += TK) {
        __syncthreads();
        #pragma unroll
        for (int c = 0; c < 2; c++) {
            int seg = w * 2 + c;
            int r = seg * 16 + srow16;
            gload16(A  + (size_t)(row0 + r) * K + k0 + sgsrc, &As[seg * 16][0]);
            gload16(Bw + (size_t)(col0 + r) * K + k0 + sgsrc, &Bs[seg * 16][0]);
        }
        __syncthreads();

        short8 af[4], bf[4];
        #pragma unroll
        for (int i = 0; i < 4; i++)
            af[i] = *(const short8*)&As[wr + i * 16 + l15][(quad * 8) ^ aswz];
        #pragma unroll
        for (int j = 0; j < 4; j++)
            bf[j] = *(const short8*)&Bs[wc + j * 16 + l15][(quad * 8) ^ aswz];
        #pragma unroll
        for (int i = 0; i < 4; i++)
            #pragma unroll
            for (int j = 0; j < 4; j++)
                acc[i][j] = __builtin_amdgcn_mfma_f32_16x16x32_bf16(af[i], bf[j], acc[i][j], 0, 0, 0);
    }

    #pragma unroll
    for (int i = 0; i < 4; i++) {
        const int rb = row0 + wr + i * 16 + quad * 4;
        #pragma unroll
        for (int j = 0; j < 4; j++) {
            const int c = col0 + wc + j * 16 + l15;
            const float bia = bias[c];
            #pragma unroll
            for (int rr = 0; rr < 4; rr++) {
                X[(size_t)(rb + rr) * Nd + c] =
                    f2bf(acc[i][j][rr] + bia + res[(size_t)(rb + rr) * Nd + c]);
            }
        }
    }
}

// ---------------------------------------------------------------------------
// Grid-split-K MFMA flash attention, 32 q/wave (2 subtiles), z-split x2.
//
// Pipeline (T3/T4 style, ONE raw barrier per tile):
//   loop top:  s_waitcnt vmcnt(0)          <- K DMA issued a full tile ago
//              s_barrier                    <- all waves' K(kt) landed
//              issue K(kt+1) DMA into Ks[other buf] (safe: all past barrier)
//              issue V/mask fragment loads for THIS tile (direct from global,
//                fragment-packed V5; latency hides under QK + softmax)
//              QK MFMA (ds_read Ks[cur]) -> exp2 softmax -> l-MFMA -> PV MFMA
// K double-buffered in LDS (16 KB); V and mask never touch LDS (no staging
// VALU, no V bank conflicts, no second barrier). l on the MFMA pipe as before.
// ---------------------------------------------------------------------------
#define KTILES 16   // 64-key tiles per z-half

__global__ __launch_bounds__(256) void attn_mfma(
    const unsigned short* __restrict__ Qb, const unsigned short* __restrict__ Kd,
    const unsigned short* __restrict__ V5, const unsigned short* __restrict__ expmask,
    unsigned short* __restrict__ Opart, float* __restrict__ Lpart)
{
    __shared__ unsigned short Ks[2][64][64];   // [buf][key][d], src-granule swizzled

    const int tid  = threadIdx.x;
    const int w    = tid >> 6;
    const int lane = tid & 63;
    const int l15  = lane & 15;
    const int quad = lane >> 4;

    const int qtile = blockIdx.x;     // 0..15 (128 queries each)
    const int bn    = blockIdx.y;
    const int z     = blockIdx.z;
    const int n     = bn & 15;
    const int b     = bn >> 4;

    const int kbase = z * (KTILES * 64);

    // Q B-fragments for both subtiles (n=l15 -> query row, k=quad*8+j)
    short8 qfrag0[2], qfrag1[2];
    {
        const int qrow0 = qtile * 128 + w * 16 + l15;
        const unsigned short* qp = Qb + (size_t)(b * Sq + qrow0) * Hq + n * HNq + quad * 8;
        qfrag0[0] = *(const short8*)(qp);
        qfrag0[1] = *(const short8*)(qp + 32);
        qp += (size_t)64 * Hq;
        qfrag1[0] = *(const short8*)(qp);
        qfrag1[1] = *(const short8*)(qp + 32);
    }

    floatx4 oacc0[4], oacc1[4];   // O^T per subtile: d = dt*16+quad*4+r, q=l15
    #pragma unroll
    for (int dt = 0; dt < 4; dt++) {
        oacc0[dt] = (floatx4){0.f,0.f,0.f,0.f};
        oacc1[dt] = (floatx4){0.f,0.f,0.f,0.f};
    }
    floatx4 lacc0 = (floatx4){0.f,0.f,0.f,0.f};
    floatx4 lacc1 = (floatx4){0.f,0.f,0.f,0.f};

    // K DMA geometry: wave w stages rows w*16..w*16+15 via 2 global_load_lds.
    const int krow8 = lane >> 3;               // 0..7
    const int kgr   = (lane & 7) ^ (krow8 & 7);
    const unsigned short* kp = Kd + (size_t)(b * Sq + kbase + w * 16 + krow8) * Hq
                                  + n * HNq + kgr * 8;
    const size_t kstep = (size_t)64 * Hq;

    // prologue: K tile 0 -> Ks[0]
    gload16(kp,                   &Ks[0][w * 16][0]);
    gload16(kp + (size_t)8 * Hq,  &Ks[0][w * 16 + 8][0]);

    // V fragment base (fragment-packed layout, 4096 elems per ktile)
    const unsigned short* Vb = V5 + ((size_t)(b * Nq + n) * 32 + z * KTILES) * 4096;
    const unsigned short* eb = expmask + (size_t)b * Sq + kbase;
    const int vfo = quad * 256 + l15 * 16;   // ks adds 8*256

    #pragma unroll 2
    for (int kt = 0; kt < KTILES; kt++) {
        asm volatile("s_waitcnt vmcnt(0)" ::: "memory");   // K(kt) landed
        __builtin_amdgcn_s_barrier();                      // all waves' K landed
        __builtin_amdgcn_sched_barrier(0);

        const int cur = kt & 1;
        if (kt + 1 < KTILES) {     // prefetch next K tile into the other buffer
            const unsigned short* kpn = kp + (size_t)(kt + 1) * kstep;
            gload16(kpn,                  &Ks[cur ^ 1][w * 16][0]);
            gload16(kpn + (size_t)8 * Hq, &Ks[cur ^ 1][w * 16 + 8][0]);
        }

        // V fragments for this tile: per ks, [dt0|dt1] lo, [dt2|dt3] lo, same hi.
        const unsigned short* vt = Vb + (size_t)kt * 4096;
        short8 vA[2], vB[2], wA[2], wB[2];
        #pragma unroll
        for (int ks = 0; ks < 2; ks++) {
            const int o = ks * 2048 + vfo;
            vA[ks] = *(const short8*)(vt + o);
            vB[ks] = *(const short8*)(vt + o + 8);
            wA[ks] = *(const short8*)(vt + o + 1024);
            wB[ks] = *(const short8*)(vt + o + 1032);
        }
        // mask fragments: 2^(m_k*log2e) for the permuted k-slots (broadcast)
        short4s ml[2], mh[2];
        #pragma unroll
        for (int ks = 0; ks < 2; ks++) {
            ml[ks] = *(const short4s*)(eb + kt * 64 + 32 * ks + quad * 4);
            mh[ks] = *(const short4s*)(eb + kt * 64 + 32 * ks + 16 + quad * 4);
        }

        // ---- S^T = K Q^T for both subtiles; each af read feeds 2 MFMAs
        floatx4 sacc0[4], sacc1[4];
        #pragma unroll
        for (int ct = 0; ct < 4; ct++) {
            sacc0[ct] = (floatx4){0.f,0.f,0.f,0.f};
            sacc1[ct] = (floatx4){0.f,0.f,0.f,0.f};
        }
        #pragma unroll
        for (int ks = 0; ks < 2; ks++) {
            #pragma unroll
            for (int ct = 0; ct < 4; ct++) {
                short8 af = *(const short8*)&Ks[cur][ct * 16 + l15][((4 * ks + quad) ^ (l15 & 7)) * 8];
                sacc0[ct] = __builtin_amdgcn_mfma_f32_16x16x32_bf16(af, qfrag0[ks], sacc0[ct], 0, 0, 0);
                sacc1[ct] = __builtin_amdgcn_mfma_f32_16x16x32_bf16(af, qfrag1[ks], sacc1[ct], 0, 0, 0);
            }
        }

        // ---- exp2-only softmax (mask in V'/mf; l via MFMA below)
        short8 pf0[2], pf1[2];   // pf[ks][(ct&1)*4+r] = P(key=16ct+4quad+r)
        #pragma unroll
        for (int ks = 0; ks < 2; ks++) {
            union { unsigned int u[4]; short8 s; } pk;
            #pragma unroll
            for (int h = 0; h < 2; h++) {
                const int ct = ks * 2 + h;
                pk.u[h * 2]     = pkbf(exp2f(sacc0[ct][0]), exp2f(sacc0[ct][1]));
                pk.u[h * 2 + 1] = pkbf(exp2f(sacc0[ct][2]), exp2f(sacc0[ct][3]));
            }
            pf0[ks] = pk.s;
        }
        #pragma unroll
        for (int ks = 0; ks < 2; ks++) {
            union { unsigned int u[4]; short8 s; } pk;
            #pragma unroll
            for (int h = 0; h < 2; h++) {
                const int ct = ks * 2 + h;
                pk.u[h * 2]     = pkbf(exp2f(sacc1[ct][0]), exp2f(sacc1[ct][1]));
                pk.u[h * 2 + 1] = pkbf(exp2f(sacc1[ct][2]), exp2f(sacc1[ct][3]));
            }
            pf1[ks] = pk.s;
        }

        // ---- l via MFMA: mf A-frag = 2^(m_k) in the SAME permuted k-slots as pf
        #pragma unroll
        for (int ks = 0; ks < 2; ks++) {
            short8 mf = __builtin_shufflevector(ml[ks], mh[ks], 0, 1, 2, 3, 4, 5, 6, 7);
            lacc0 = __builtin_amdgcn_mfma_f32_16x16x32_bf16(mf, pf0[ks], lacc0, 0, 0, 0);
            lacc1 = __builtin_amdgcn_mfma_f32_16x16x32_bf16(mf, pf1[ks], lacc1, 0, 0, 0);
        }

        // ---- O^T += V'^T P^T; vf built from packed V fragments (registers)
        #pragma unroll
        for (int ks = 0; ks < 2; ks++) {
            short8 vf0 = __builtin_shufflevector(vA[ks], wA[ks], 0, 1, 2, 3, 8, 9, 10, 11);
            short8 vf1 = __builtin_shufflevector(vA[ks], wA[ks], 4, 5, 6, 7, 12, 13, 14, 15);
            short8 vf2 = __builtin_shufflevector(vB[ks], wB[ks], 0, 1, 2, 3, 8, 9, 10, 11);
            short8 vf3 = __builtin_shufflevector(vB[ks], wB[ks], 4, 5, 6, 7, 12, 13, 14, 15);
            oacc0[0] = __builtin_amdgcn_mfma_f32_16x16x32_bf16(vf0, pf0[ks], oacc0[0], 0, 0, 0);
            oacc1[0] = __builtin_amdgcn_mfma_f32_16x16x32_bf16(vf0, pf1[ks], oacc1[0], 0, 0, 0);
            oacc0[1] = __builtin_amdgcn_mfma_f32_16x16x32_bf16(vf1, pf0[ks], oacc0[1], 0, 0, 0);
            oacc1[1] = __builtin_amdgcn_mfma_f32_16x16x32_bf16(vf1, pf1[ks], oacc1[1], 0, 0, 0);
            oacc0[2] = __builtin_amdgcn_mfma_f32_16x16x32_bf16(vf2, pf0[ks], oacc0[2], 0, 0, 0);
            oacc1[2] = __builtin_amdgcn_mfma_f32_16x16x32_bf16(vf2, pf1[ks], oacc1[2], 0, 0, 0);
            oacc0[3] = __builtin_amdgcn_mfma_f32_16x16x32_bf16(vf3, pf0[ks], oacc0[3], 0, 0, 0);
            oacc1[3] = __builtin_amdgcn_mfma_f32_16x16x32_bf16(vf3, pf1[ks], oacc1[3], 0, 0, 0);
        }
    }

    // ---- epilogue: un-normalized partial O (bf16) + per-query l (no shfls:
    // every row of lacc holds l_q for q=l15)
    unsigned short* Ow = Opart + (size_t)z * Mq * Hq;
    #pragma unroll
    for (int sub = 0; sub < 2; sub++) {
        const float l_i = sub ? lacc1[0] : lacc0[0];
        const int qrow = qtile * 128 + sub * 64 + w * 16 + l15;
        if (quad == 0)
            Lpart[(size_t)z * Mq * Nq + (size_t)(b * Sq + qrow) * Nq + n] = l_i;
        #pragma unroll
        for (int dt = 0; dt < 4; dt++) {
            const floatx4 oa = sub ? oacc1[dt] : oacc0[dt];
            union { unsigned int u[2]; ushortx4 s; } o;
            o.u[0] = pkbf(oa[0], oa[1]);
            o.u[1] = pkbf(oa[2], oa[3]);
            const int col = n * HNq + dt * 16 + quad * 4;
            *(ushortx4*)&Ow[(size_t)(b * Sq + qrow) * Hq + col] = o.s;
        }
    }
}

// ---------------------------------------------------------------------------
// Merge the two split-K halves: ctx = (O0 + O1) / (l0 + l1), bf16 out.
// ---------------------------------------------------------------------------
__global__ __launch_bounds__(256) void attn_merge(
    const unsigned short* __restrict__ Opart, const float* __restrict__ Lpart,
    unsigned short* __restrict__ ctx)
{
    const size_t idx = ((size_t)blockIdx.x * 256 + threadIdx.x) * 4;
    const int row = (int)(idx >> 10);          // b*Sq + s
    const int n   = ((int)idx >> 6) & 15;
    const float l = Lpart[(size_t)row * Nq + n]
                  + Lpart[(size_t)Mq * Nq + (size_t)row * Nq + n];
    const float inv = 1.0f / l;
    ushortx4 a = *(const ushortx4*)(Opart + idx);
    ushortx4 c = *(const ushortx4*)(Opart + (size_t)Mq * Hq + idx);
    union { unsigned int u[2]; ushortx4 s; } o;
    o.u[0] = pkbf((bf2f(a[0]) + bf2f(c[0])) * inv, (bf2f(a[1]) + bf2f(c[1])) * inv);
    o.u[1] = pkbf((bf2f(a[2]) + bf2f(c[2])) * inv, (bf2f(a[3]) + bf2f(c[3])) * inv);
    *(ushortx4*)(ctx + idx) = o.s;
}

// ---------------------------------------------------------------------------
// Row LayerNorm over H=1024, bf16 input, fp32 stats, fp32 output.
// ---------------------------------------------------------------------------
__global__ __launch_bounds__(256) void ln_kernel(
    const unsigned short* __restrict__ X, const float* __restrict__ gamma,
    const float* __restrict__ beta, float* __restrict__ out)
{
    const int row = blockIdx.x;
    const int c0  = threadIdx.x * 4;
    ushortx4 xv = *(const ushortx4*)(X + (size_t)row * Hq + c0);
    float vals[4];
    float lsum = 0.0f;
    #pragma unroll
    for (int i = 0; i < 4; i++) { vals[i] = bf2f(xv[i]); lsum += vals[i]; }

    __shared__ float red[8];
    const int wid = threadIdx.x >> 6, lane = threadIdx.x & 63;

    float s = lsum;
    #pragma unroll
    for (int off = 32; off >= 1; off >>= 1) s += __shfl_xor(s, off, 64);
    if (lane == 0) red[wid] = s;
    __syncthreads();
    const float mean = (red[0] + red[1] + red[2] + red[3]) * (1.0f / Hq);

    float v = 0.0f;
    #pragma unroll
    for (int i = 0; i < 4; i++) { float d = vals[i] - mean; v += d * d; }
    #pragma unroll
    for (int off = 32; off >= 1; off >>= 1) v += __shfl_xor(v, off, 64);
    if (lane == 0) red[4 + wid] = v;
    __syncthreads();
    const float var  = (red[4] + red[5] + red[6] + red[7]) * (1.0f / Hq);
    const float rstd = rsqrtf(var + 1e-12f);

    float4 gm = *(const float4*)(gamma + c0);
    float4 bt = *(const float4*)(beta + c0);
    float4 o;
    o.x = (vals[0] - mean) * rstd * gm.x + bt.x;
    o.y = (vals[1] - mean) * rstd * gm.y + bt.y;
    o.z = (vals[2] - mean) * rstd * gm.z + bt.z;
    o.w = (vals[3] - mean) * rstd * gm.w + bt.w;
    *(float4*)(out + (size_t)row * Hq + c0) = o;
}

// ---------------------------------------------------------------------------
extern "C" void kernel_launch(void* const* d_in, const int* in_sizes, int n_in,
                              void* d_out, int out_size, void* d_ws, size_t ws_size,
                              hipStream_t stream)
{
    const float* hidden = (const float*)d_in[0];
    const float* mask   = (const float*)d_in[1];
    const float* W_qkv  = (const float*)d_in[2];
    const float* b_qkv  = (const float*)d_in[3];
    const float* W_out  = (const float*)d_in[4];
    const float* b_out  = (const float*)d_in[5];
    const float* gamma  = (const float*)d_in[6];
    const float* beta   = (const float*)d_in[7];
    float* out = (float*)d_out;

    const size_t nHid  = (size_t)Mq * Hq;        // 4 M
    const size_t nWq   = (size_t)H3q * Hq;       // 3 M
    const size_t nWo   = (size_t)Hq * Hq;        // 1 M
    const size_t nCtx  = (size_t)Mq * Hq;        // 4 M

    unsigned short* hidden_bf = (unsigned short*)d_ws;
    unsigned short* Wqkv_bf   = hidden_bf + nHid;
    unsigned short* Wout_bf   = Wqkv_bf + nWq;
    unsigned short* qb        = Wout_bf + nWo;          // Q  [4096][1024]
    unsigned short* kd        = qb + nHid;              // K  [4096][1024]
    unsigned short* v5        = kd + nHid;              // V' fragment-packed, 4 M
    unsigned short* ctx_bf    = v5 + nHid;
    unsigned short* x_bf      = ctx_bf + nCtx;
    unsigned short* opart     = x_bf + nHid;            // 2 * 4M bf16 = 16 MB
    float*          lpart     = (float*)(opart + 2 * nHid);  // 2*64K floats
    unsigned short* expm_bf   = (unsigned short*)(lpart + 2 * (size_t)Mq * Nq);

    dim3 blk(256);

    // 0) fused fp32 -> bf16 cast + expmask precompute
    cvt_all<<<dim3((int)(N_ALL / 2048)), blk, 0, stream>>>(
        hidden, W_qkv, W_out, hidden_bf);
    cvt_mask<<<dim3(2), blk, 0, stream>>>(mask, expm_bf);

    // 1) QKV projection (MFMA) -> Qb / Kd / V5 (e^mask folded into V')
    gemm_mfma_qkv<<<dim3(H3q / TN, Mq / TM), blk, 0, stream>>>(
        hidden_bf, Wqkv_bf, b_qkv, mask, qb, kd, v5, Hq);

    // 2) Grid-split-K MFMA flash attention (32 q/wave) -> partial O/l
    attn_mfma<<<dim3(Sq / 128, Bq * Nq, 2), blk, 0, stream>>>(
        qb, kd, v5, expm_bf, opart, lpart);

    // 2b) merge halves -> ctx bf16
    attn_merge<<<dim3((int)(nCtx / 1024)), blk, 0, stream>>>(
        opart, lpart, ctx_bf);

    // 3) Output projection (MFMA) + bias + residual -> x bf16
    gemm_mfma_out<<<dim3(Hq / TN, Mq / TM), blk, 0, stream>>>(
        ctx_bf, Wout_bf, b_out, hidden, x_bf, Mq, Hq, Hq);

    // 4) LayerNorm: bf16 x -> fp32 out
    ln_kernel<<<dim3(Mq), blk, 0, stream>>>(x_bf, gamma, beta, out);
}

// Round 2
// 246.188 us; speedup vs baseline: 1.0078x; 1.0078x over previous
//
#include <hip/hip_runtime.h>
#include <hip/hip_bf16.h>
#include <math.h>

// Problem constants
#define Bq  2
#define Sq  2048
#define Hq  1024
#define Nq  16
#define HNq 64
#define Mq  (Bq*Sq)        // 4096 rows
#define H3q (3*Hq)         // 3072

#define LOG2E 1.44269504088896340736f

typedef __attribute__((ext_vector_type(8))) short           short8;
typedef __attribute__((ext_vector_type(4))) short           short4s;
typedef __attribute__((ext_vector_type(8))) unsigned short  ushortx8;
typedef __attribute__((ext_vector_type(4))) unsigned short  ushortx4;
typedef __attribute__((ext_vector_type(4))) float           floatx4;

__device__ __forceinline__ unsigned short f2bf(float f) {
    union { float f; unsigned int u; } x; x.f = f;
    unsigned int r = (x.u + 0x7fffu + ((x.u >> 16) & 1u)) >> 16;
    return (unsigned short)r;
}

// packed fp32x2 -> bf16x2 (v_cvt_pk_bf16_f32 on gfx950); a in low 16 bits
__device__ __forceinline__ unsigned int pkbf(float a, float b) {
    float2 t; t.x = a; t.y = b;
    __hip_bfloat162 h = __float22bfloat162_rn(t);
    union { __hip_bfloat162 h; unsigned int u; } c; c.h = h;
    return c.u;
}

__device__ __forceinline__ float bf2f(unsigned short v) {
    union { unsigned int u; float f; } x; x.u = (unsigned int)v << 16;
    return x.f;
}

// async global->LDS, 16B per lane; LDS dest = wave-uniform base + lane*16
__device__ __forceinline__ void gload16(const unsigned short* g, unsigned short* l) {
    __builtin_amdgcn_global_load_lds(
        (__attribute__((address_space(1))) void*)(unsigned long long)(g),
        (__attribute__((address_space(3))) void*)(unsigned int)(unsigned long long)(l),
        16, 0, 0);
}

// LDS bank swizzle: granule' = granule ^ swz(row mod 16); 2-way max conflict
__device__ __forceinline__ int swz(int r) { return (r ^ (r >> 2)) & 3; }

// ---------------------------------------------------------------------------
// Fused fp32 -> bf16 cast for hidden | W_qkv | W_out (contiguous bf16 dst)
// ---------------------------------------------------------------------------
#define N_HID ((size_t)Mq * Hq)          // 4194304
#define N_HW  (N_HID + (size_t)H3q * Hq) // 7340032
#define N_ALL (N_HW + (size_t)Hq * Hq)   // 8388608

__global__ __launch_bounds__(256) void cvt_all(
    const float* __restrict__ hidden, const float* __restrict__ wqkv,
    const float* __restrict__ wout, unsigned short* __restrict__ dst)
{
    size_t i = ((size_t)blockIdx.x * 256 + threadIdx.x) * 8;
    const float* src;
    if (i < N_HID)      src = hidden + i;
    else if (i < N_HW)  src = wqkv + (i - N_HID);
    else                src = wout + (i - N_HW);
    float4 a = *(const float4*)(src);
    float4 b = *(const float4*)(src + 4);
    union { unsigned int u[4]; ushortx8 s; } o;
    o.u[0] = pkbf(a.x, a.y); o.u[1] = pkbf(a.z, a.w);
    o.u[2] = pkbf(b.x, b.y); o.u[3] = pkbf(b.z, b.w);
    *(ushortx8*)(dst + i) = o.s;
}

// em2: e^mask in PERMUTED mf-fragment order so attention's l-MFMA A-fragment
// is a direct 16B load.  em2[((b*32+kt)*2+ks)*32 + quad*8 + hi*4 + r]
//   = exp(mask[b][kt*64 + (2ks+hi)*16 + quad*4 + r])
__global__ __launch_bounds__(256) void cvt_mask(
    const float* __restrict__ mask, unsigned short* __restrict__ em2)
{
    const int t0   = (blockIdx.x * 256 + threadIdx.x) * 8;   // 4096 outputs
    const int b    = t0 >> 11;
    const int t2   = t0 & 2047;
    const int kt   = t2 >> 6;
    const int t3   = t2 & 63;
    const int ks   = t3 >> 5;
    const int quad = (t3 >> 3) & 3;
    const int kb   = kt * 64 + ks * 32 + quad * 4;
    const float* mp = mask + (size_t)b * Sq + kb;
    float4 m0 = *(const float4*)(mp);
    float4 m1 = *(const float4*)(mp + 16);
    union { unsigned int u[4]; ushortx8 s; } o;
    o.u[0] = pkbf(exp2f(m0.x * LOG2E), exp2f(m0.y * LOG2E));
    o.u[1] = pkbf(exp2f(m0.z * LOG2E), exp2f(m0.w * LOG2E));
    o.u[2] = pkbf(exp2f(m1.x * LOG2E), exp2f(m1.y * LOG2E));
    o.u[3] = pkbf(exp2f(m1.z * LOG2E), exp2f(m1.w * LOG2E));
    *(ushortx8*)(em2 + t0) = o.s;
}

// ---------------------------------------------------------------------------
// MFMA GEMM core: 128x128 tile, BK=32, 4 waves each computing 64x64.
// ---------------------------------------------------------------------------
#define TM 128
#define TN 128
#define TK 32

// GEMM1: QKV projection. Outputs:
//   Qb [row][1024]  Q * 0.125*log2e (bf16)
//   Kd [row][1024]  K (bf16), dense rows for contiguous global_load_lds
//   V5 fragment-packed V'^T (e^mask folded): element (b,n,kt32,s,d) at
//     ((b*16+n)*32+kt32)*4096 + (ks*16+dt*4+q2)*128 + dl*8 + hi*4 + r
//     with kg=s>>2, r=s&3, ks=kg>>3, q2=kg&3, hi=(kg>>2)&1, dt=d>>4, dl=d&15.
//   => attention's PV A-fragments are direct 16B loads in final MFMA order.
__global__ __launch_bounds__(256) void gemm_mfma_qkv(
    const unsigned short* __restrict__ A, const unsigned short* __restrict__ Bw,
    const float* __restrict__ bias, const float* __restrict__ mask,
    unsigned short* __restrict__ Qb, unsigned short* __restrict__ Kd,
    unsigned short* __restrict__ V5, int K)
{
    __shared__ unsigned short As[TM][TK];
    __shared__ unsigned short Bs[TN][TK];

    const int tid = threadIdx.x;
    const int w = tid >> 6, lane = tid & 63;
    const int l15 = lane & 15, quad = lane >> 4;
    const int wr = (w & 1) * 64;
    const int wc = (w >> 1) * 64;
    const int row0 = blockIdx.y * TM;
    const int col0 = blockIdx.x * TN;

    const int srow16 = lane >> 2;
    const int sgd    = lane & 3;
    const int sgsrc  = (sgd ^ swz(srow16)) * 8;

    floatx4 acc[4][4];
    #pragma unroll
    for (int i = 0; i < 4; i++)
        #pragma unroll
        for (int j = 0; j < 4; j++) acc[i][j] = (floatx4){0.f,0.f,0.f,0.f};

    const int aswz = swz(l15) * 8;

    for (int k0 = 0; k0 < K; k0 += TK) {
        __syncthreads();
        #pragma unroll
        for (int c = 0; c < 2; c++) {
            int seg = w * 2 + c;
            int r = seg * 16 + srow16;
            gload16(A  + (size_t)(row0 + r) * K + k0 + sgsrc, &As[seg * 16][0]);
            gload16(Bw + (size_t)(col0 + r) * K + k0 + sgsrc, &Bs[seg * 16][0]);
        }
        __syncthreads();

        short8 af[4], bf[4];
        #pragma unroll
        for (int i = 0; i < 4; i++)
            af[i] = *(const short8*)&As[wr + i * 16 + l15][(quad * 8) ^ aswz];
        #pragma unroll
        for (int j = 0; j < 4; j++)
            bf[j] = *(const short8*)&Bs[wc + j * 16 + l15][(quad * 8) ^ aswz];
        #pragma unroll
        for (int i = 0; i < 4; i++)
            #pragma unroll
            for (int j = 0; j < 4; j++)
                acc[i][j] = __builtin_amdgcn_mfma_f32_16x16x32_bf16(af[i], bf[j], acc[i][j], 0, 0, 0);
    }

    const int cls = col0 >> 10;    // 0=Q, 1=K, 2=V; uniform per block

    if (cls == 2) {
        #pragma unroll
        for (int i = 0; i < 4; i++) {
            const int rb = row0 + wr + i * 16 + quad * 4;
            const int b  = rb >> 11;
            const int s  = rb & (Sq - 1);
            const int kt32 = s >> 6;
            const int sw   = s & 63;
            const int kg   = sw >> 2;          // s&3 == 0 (rb % 4 == 0)
            const int ks   = kg >> 3;
            const int q2   = kg & 3;
            const int hi   = (kg >> 2) & 1;
            float expm[4];
            #pragma unroll
            for (int rr = 0; rr < 4; rr++)
                expm[rr] = exp2f(mask[(size_t)b * Sq + s + rr] * LOG2E);
            #pragma unroll
            for (int j = 0; j < 4; j++) {
                const int c  = col0 + wc + j * 16 + l15;
                const int c2 = c - 2 * Hq;           // n*64+d
                const int n  = c2 >> 6, d = c2 & 63;
                const int dt = d >> 4, dl = d & 15;
                const float bia = bias[c];
                ushortx4 o;
                #pragma unroll
                for (int rr = 0; rr < 4; rr++)
                    o[rr] = f2bf((acc[i][j][rr] + bia) * expm[rr]);
                const size_t off = (((size_t)(b * Nq + n) * 32 + kt32) << 12)
                                 + (size_t)((ks * 16 + dt * 4 + q2) * 128 + dl * 8 + hi * 4);
                *(ushortx4*)&V5[off] = o;
            }
        }
    } else {
        unsigned short* __restrict__ dst = (cls == 0) ? Qb : Kd;
        const int cshift = (cls == 0) ? 0 : Hq;
        const float qs = (cls == 0) ? (0.125f * LOG2E) : 1.0f;
        #pragma unroll
        for (int i = 0; i < 4; i++) {
            const int rb = row0 + wr + i * 16 + quad * 4;
            #pragma unroll
            for (int j = 0; j < 4; j++) {
                const int c = col0 + wc + j * 16 + l15;
                const float bia = bias[c];
                #pragma unroll
                for (int rr = 0; rr < 4; rr++)
                    dst[(size_t)(rb + rr) * Hq + (c - cshift)] =
                        f2bf((acc[i][j][rr] + bia) * qs);
            }
        }
    }
}

// GEMM2: x = A*Bw^T + bias + residual -> bf16 (LN reads bf16, stats in fp32)
__global__ __launch_bounds__(256) void gemm_mfma_out(
    const unsigned short* __restrict__ A, const unsigned short* __restrict__ Bw,
    const float* __restrict__ bias, const float* __restrict__ res,
    unsigned short* __restrict__ X, int M, int Nd, int K)
{
    __shared__ unsigned short As[TM][TK];
    __shared__ unsigned short Bs[TN][TK];

    const int tid = threadIdx.x;
    const int w = tid >> 6, lane = tid & 63;
    const int l15 = lane & 15, quad = lane >> 4;
    const int wr = (w & 1) * 64;
    const int wc = (w >> 1) * 64;
    const int row0 = blockIdx.y * TM;
    const int col0 = blockIdx.x * TN;

    const int srow16 = lane >> 2;
    const int sgd    = lane & 3;
    const int sgsrc  = (sgd ^ swz(srow16)) * 8;

    floatx4 acc[4][4];
    #pragma unroll
    for (int i = 0; i < 4; i++)
        #pragma unroll
        for (int j = 0; j < 4; j++) acc[i][j] = (floatx4){0.f,0.f,0.f,0.f};

    const int aswz = swz(l15) * 8;

    for (int k0 = 0; k0 < K; k0 += TK) {
        __syncthreads();
        #pragma unroll
        for (int c = 0; c < 2; c++) {
            int seg = w * 2 + c;
            int r = seg * 16 + srow16;
            gload16(A  + (size_t)(row0 + r) * K + k0 + sgsrc, &As[seg * 16][0]);
            gload16(Bw + (size_t)(col0 + r) * K + k0 + sgsrc, &Bs[seg * 16][0]);
        }
        __syncthreads();

        short8 af[4], bf[4];
        #pragma unroll
        for (int i = 0; i < 4; i++)
            af[i] = *(const short8*)&As[wr + i * 16 + l15][(quad * 8) ^ aswz];
        #pragma unroll
        for (int j = 0; j < 4; j++)
            bf[j] = *(const short8*)&Bs[wc + j * 16 + l15][(quad * 8) ^ aswz];
        #pragma unroll
        for (int i = 0; i < 4; i++)
            #pragma unroll
            for (int j = 0; j < 4; j++)
                acc[i][j] = __builtin_amdgcn_mfma_f32_16x16x32_bf16(af[i], bf[j], acc[i][j], 0, 0, 0);
    }

    #pragma unroll
    for (int i = 0; i < 4; i++) {
        const int rb = row0 + wr + i * 16 + quad * 4;
        #pragma unroll
        for (int j = 0; j < 4; j++) {
            const int c = col0 + wc + j * 16 + l15;
            const float bia = bias[c];
            #pragma unroll
            for (int rr = 0; rr < 4; rr++) {
                X[(size_t)(rb + rr) * Nd + c] =
                    f2bf(acc[i][j][rr] + bia + res[(size_t)(rb + rr) * Nd + c]);
            }
        }
    }
}

// ---------------------------------------------------------------------------
// Grid-split-K MFMA flash attention with CROSS-TILE software pipeline:
// body(kt) = { wait K(kt) [vmcnt(10): only the 2 K-DMAs, vf/mf stay in
// flight]; barrier; prefetch K(kt+1); load mf(kt); QK(kt) MFMA -> sacc;
// softmax(kt) -> pf_W (VALU/trans); l+PV(kt-1) MFMA from pf_R + vf(kt-1)
// [independent of this tile's QK->exp chain => MFMA fills the exp2 shadow];
// reload vf(kt) [full tile of latency cover]. }
// ---------------------------------------------------------------------------
#define KTILES 16   // 64-key tiles per z-half

__device__ __forceinline__ floatx4 mfma16(short8 a, short8 b, floatx4 c) {
    return __builtin_amdgcn_mfma_f32_16x16x32_bf16(a, b, c, 0, 0, 0);
}

// l-MFMA + PV for the PREVIOUS tile (pf/mf/vf all in final fragment order)
__device__ __forceinline__ void do_lpv(
    const short8 (&pf0)[2], const short8 (&pf1)[2], const short8 (&mf)[2],
    const short8 (&vf)[8],
    floatx4 (&oacc0)[4], floatx4 (&oacc1)[4],
    floatx4 &lacc0, floatx4 &lacc1)
{
    __builtin_amdgcn_s_setprio(1);
    lacc0 = mfma16(mf[0], pf0[0], lacc0);
    lacc0 = mfma16(mf[1], pf0[1], lacc0);
    lacc1 = mfma16(mf[0], pf1[0], lacc1);
    lacc1 = mfma16(mf[1], pf1[1], lacc1);
    #pragma unroll
    for (int dt = 0; dt < 4; dt++) {
        oacc0[dt] = mfma16(vf[dt],     pf0[0], oacc0[dt]);
        oacc1[dt] = mfma16(vf[dt],     pf1[0], oacc1[dt]);
        oacc0[dt] = mfma16(vf[4 + dt], pf0[1], oacc0[dt]);
        oacc1[dt] = mfma16(vf[4 + dt], pf1[1], oacc1[dt]);
    }
    __builtin_amdgcn_s_setprio(0);
}

template<bool HAVER, bool PREF, int VWAIT>
__device__ __forceinline__ void attn_body(
    int kt,
    unsigned short (&KsL)[2][64][64],
    const unsigned short* kp, size_t kstep,
    const unsigned short* Vb, const unsigned short* e2b,
    int w, int l15, int quad,
    const short8 (&qf0)[2], const short8 (&qf1)[2],
    short8 (&vf)[8],
    const short8 (&pfR0)[2], const short8 (&pfR1)[2], const short8 (&mfR)[2],
    short8 (&pfW0)[2], short8 (&pfW1)[2], short8 (&mfW)[2],
    floatx4 (&oacc0)[4], floatx4 (&oacc1)[4],
    floatx4 &lacc0, floatx4 &lacc1)
{
    asm volatile("s_waitcnt vmcnt(%0)" :: "i"(VWAIT) : "memory");
    __builtin_amdgcn_s_barrier();
    __builtin_amdgcn_sched_barrier(0);

    const int cur = kt & 1;
    if (PREF) {
        const unsigned short* kpn = kp + (size_t)(kt + 1) * kstep;
        gload16(kpn,                  &KsL[cur ^ 1][w * 16][0]);
        gload16(kpn + (size_t)8 * Hq, &KsL[cur ^ 1][w * 16 + 8][0]);
    }
    __builtin_amdgcn_sched_barrier(0);   // pin K-DMAs as oldest outstanding

    // mf for THIS tile (consumed next body): direct loads, final order
    const unsigned short* ep = e2b + kt * 64;
    mfW[0] = *(const short8*)(ep + quad * 8);
    mfW[1] = *(const short8*)(ep + 32 + quad * 8);

    // ---- QK(kt): S^T = K Q^T for both subtiles
    floatx4 s0[4], s1[4];
    #pragma unroll
    for (int ct = 0; ct < 4; ct++) {
        s0[ct] = (floatx4){0.f,0.f,0.f,0.f};
        s1[ct] = (floatx4){0.f,0.f,0.f,0.f};
    }
    __builtin_amdgcn_s_setprio(1);
    #pragma unroll
    for (int ks = 0; ks < 2; ks++) {
        #pragma unroll
        for (int ct = 0; ct < 4; ct++) {
            short8 af = *(const short8*)&KsL[cur][ct * 16 + l15][((4 * ks + quad) ^ (l15 & 7)) * 8];
            s0[ct] = mfma16(af, qf0[ks], s0[ct]);
            s1[ct] = mfma16(af, qf1[ks], s1[ct]);
        }
    }
    __builtin_amdgcn_s_setprio(0);

    // ---- softmax(kt) -> pfW (exp2-only; mask folded into V'/mf)
    #pragma unroll
    for (int ks = 0; ks < 2; ks++) {
        union { unsigned int u[4]; short8 s; } pk;
        #pragma unroll
        for (int h = 0; h < 2; h++) {
            const int ct = ks * 2 + h;
            pk.u[h * 2]     = pkbf(exp2f(s0[ct][0]), exp2f(s0[ct][1]));
            pk.u[h * 2 + 1] = pkbf(exp2f(s0[ct][2]), exp2f(s0[ct][3]));
        }
        pfW0[ks] = pk.s;
    }
    #pragma unroll
    for (int ks = 0; ks < 2; ks++) {
        union { unsigned int u[4]; short8 s; } pk;
        #pragma unroll
        for (int h = 0; h < 2; h++) {
            const int ct = ks * 2 + h;
            pk.u[h * 2]     = pkbf(exp2f(s1[ct][0]), exp2f(s1[ct][1]));
            pk.u[h * 2 + 1] = pkbf(exp2f(s1[ct][2]), exp2f(s1[ct][3]));
        }
        pfW1[ks] = pk.s;
    }

    // ---- l + PV for tile kt-1 (overlaps the exp2 chain above)
    if (HAVER)
        do_lpv(pfR0, pfR1, mfR, vf, oacc0, oacc1, lacc0, lacc1);

    // ---- vf(kt): direct fragment loads (consumed next body => full cover)
    const unsigned short* vt = Vb + (size_t)kt * 4096 + quad * 128 + l15 * 8;
    vf[0] = *(const short8*)(vt);
    vf[1] = *(const short8*)(vt + 512);
    vf[2] = *(const short8*)(vt + 1024);
    vf[3] = *(const short8*)(vt + 1536);
    vf[4] = *(const short8*)(vt + 2048);
    vf[5] = *(const short8*)(vt + 2560);
    vf[6] = *(const short8*)(vt + 3072);
    vf[7] = *(const short8*)(vt + 3584);
}

__global__ __launch_bounds__(256) void attn_mfma(
    const unsigned short* __restrict__ Qb, const unsigned short* __restrict__ Kd,
    const unsigned short* __restrict__ V5, const unsigned short* __restrict__ em2,
    unsigned short* __restrict__ Opart, float* __restrict__ Lpart)
{
    __shared__ unsigned short Ks[2][64][64];   // [buf][key][d], src-granule swizzled

    const int tid  = threadIdx.x;
    const int w    = tid >> 6;
    const int lane = tid & 63;
    const int l15  = lane & 15;
    const int quad = lane >> 4;

    const int qtile = blockIdx.x;     // 0..15 (128 queries each)
    const int bn    = blockIdx.y;
    const int z     = blockIdx.z;
    const int n     = bn & 15;
    const int b     = bn >> 4;

    const int kbase = z * (KTILES * 64);

    // Q B-fragments for both subtiles (n=l15 -> query row, k=quad*8+j)
    short8 qf0[2], qf1[2];
    {
        const int qrow0 = qtile * 128 + w * 16 + l15;
        const unsigned short* qp = Qb + (size_t)(b * Sq + qrow0) * Hq + n * HNq + quad * 8;
        qf0[0] = *(const short8*)(qp);
        qf0[1] = *(const short8*)(qp + 32);
        qp += (size_t)64 * Hq;
        qf1[0] = *(const short8*)(qp);
        qf1[1] = *(const short8*)(qp + 32);
    }

    floatx4 oacc0[4], oacc1[4];   // O^T per subtile: d = dt*16+quad*4+r, q=l15
    #pragma unroll
    for (int dt = 0; dt < 4; dt++) {
        oacc0[dt] = (floatx4){0.f,0.f,0.f,0.f};
        oacc1[dt] = (floatx4){0.f,0.f,0.f,0.f};
    }
    floatx4 lacc0 = (floatx4){0.f,0.f,0.f,0.f};
    floatx4 lacc1 = (floatx4){0.f,0.f,0.f,0.f};

    // K DMA geometry: wave w stages rows w*16..w*16+15 via 2 global_load_lds.
    const int krow8 = lane >> 3;               // 0..7
    const int kgr   = (lane & 7) ^ (krow8 & 7);
    const unsigned short* kp = Kd + (size_t)(b * Sq + kbase + w * 16 + krow8) * Hq
                                  + n * HNq + kgr * 8;
    const size_t kstep = (size_t)64 * Hq;

    // prologue: K tile 0 -> Ks[0]
    gload16(kp,                  &Ks[0][w * 16][0]);
    gload16(kp + (size_t)8 * Hq, &Ks[0][w * 16 + 8][0]);

    // fragment-packed V base + permuted mask base
    const unsigned short* Vb  = V5 + ((size_t)(b * Nq + n) * 32 + z * KTILES) * 4096;
    const unsigned short* e2b = em2 + (size_t)(b * 32 + z * KTILES) * 64;

    // pipeline state (two named stages, no dynamic indexing)
    short8 vf[8];
    short8 pfA0[2], pfA1[2], mfA[2];
    short8 pfB0[2], pfB1[2], mfB[2];

    // peel kt=0: fills stage A + vf(0); no PV yet
    attn_body<false, true, 0>(0, Ks, kp, kstep, Vb, e2b, w, l15, quad,
        qf0, qf1, vf, pfB0, pfB1, mfB, pfA0, pfA1, mfA, oacc0, oacc1, lacc0, lacc1);

    #pragma unroll 1
    for (int kt = 1; kt < KTILES - 1; kt += 2) {
        attn_body<true, true, 10>(kt, Ks, kp, kstep, Vb, e2b, w, l15, quad,
            qf0, qf1, vf, pfA0, pfA1, mfA, pfB0, pfB1, mfB, oacc0, oacc1, lacc0, lacc1);
        attn_body<true, true, 10>(kt + 1, Ks, kp, kstep, Vb, e2b, w, l15, quad,
            qf0, qf1, vf, pfB0, pfB1, mfB, pfA0, pfA1, mfA, oacc0, oacc1, lacc0, lacc1);
    }
    // kt = 15 (odd): reads A, writes B, no K prefetch
    attn_body<true, false, 10>(KTILES - 1, Ks, kp, kstep, Vb, e2b, w, l15, quad,
        qf0, qf1, vf, pfA0, pfA1, mfA, pfB0, pfB1, mfB, oacc0, oacc1, lacc0, lacc1);
    // drain: l + PV of the last tile (stage B, vf(15))
    do_lpv(pfB0, pfB1, mfB, vf, oacc0, oacc1, lacc0, lacc1);

    // ---- epilogue: un-normalized partial O (bf16) + per-query l (no shfls:
    // every row of lacc holds l_q for q=l15)
    unsigned short* Ow = Opart + (size_t)z * Mq * Hq;
    #pragma unroll
    for (int sub = 0; sub < 2; sub++) {
        const float l_i = sub ? lacc1[0] : lacc0[0];
        const int qrow = qtile * 128 + sub * 64 + w * 16 + l15;
        if (quad == 0)
            Lpart[(size_t)z * Mq * Nq + (size_t)(b * Sq + qrow) * Nq + n] = l_i;
        #pragma unroll
        for (int dt = 0; dt < 4; dt++) {
            const floatx4 oa = sub ? oacc1[dt] : oacc0[dt];
            union { unsigned int u[2]; ushortx4 s; } o;
            o.u[0] = pkbf(oa[0], oa[1]);
            o.u[1] = pkbf(oa[2], oa[3]);
            const int col = n * HNq + dt * 16 + quad * 4;
            *(ushortx4*)&Ow[(size_t)(b * Sq + qrow) * Hq + col] = o.s;
        }
    }
}

// ---------------------------------------------------------------------------
// Merge the two split-K halves: ctx = (O0 + O1) / (l0 + l1), bf16 out.
// ---------------------------------------------------------------------------
__global__ __launch_bounds__(256) void attn_merge(
    const unsigned short* __restrict__ Opart, const float* __restrict__ Lpart,
    unsigned short* __restrict__ ctx)
{
    const size_t idx = ((size_t)blockIdx.x * 256 + threadIdx.x) * 4;
    const int row = (int)(idx >> 10);          // b*Sq + s
    const int n   = ((int)idx >> 6) & 15;
    const float l = Lpart[(size_t)row * Nq + n]
                  + Lpart[(size_t)Mq * Nq + (size_t)row * Nq + n];
    const float inv = 1.0f / l;
    ushortx4 a = *(const ushortx4*)(Opart + idx);
    ushortx4 c = *(const ushortx4*)(Opart + (size_t)Mq * Hq + idx);
    union { unsigned int u[2]; ushortx4 s; } o;
    o.u[0] = pkbf((bf2f(a[0]) + bf2f(c[0])) * inv, (bf2f(a[1]) + bf2f(c[1])) * inv);
    o.u[1] = pkbf((bf2f(a[2]) + bf2f(c[2])) * inv, (bf2f(a[3]) + bf2f(c[3])) * inv);
    *(ushortx4*)(ctx + idx) = o.s;
}

// ---------------------------------------------------------------------------
// Row LayerNorm over H=1024, bf16 input, fp32 stats, fp32 output.
// ---------------------------------------------------------------------------
__global__ __launch_bounds__(256) void ln_kernel(
    const unsigned short* __restrict__ X, const float* __restrict__ gamma,
    const float* __restrict__ beta, float* __restrict__ out)
{
    const int row = blockIdx.x;
    const int c0  = threadIdx.x * 4;
    ushortx4 xv = *(const ushortx4*)(X + (size_t)row * Hq + c0);
    float vals[4];
    float lsum = 0.0f;
    #pragma unroll
    for (int i = 0; i < 4; i++) { vals[i] = bf2f(xv[i]); lsum += vals[i]; }

    __shared__ float red[8];
    const int wid = threadIdx.x >> 6, lane = threadIdx.x & 63;

    float s = lsum;
    #pragma unroll
    for (int off = 32; off >= 1; off >>= 1) s += __shfl_xor(s, off, 64);
    if (lane == 0) red[wid] = s;
    __syncthreads();
    const float mean = (red[0] + red[1] + red[2] + red[3]) * (1.0f / Hq);

    float v = 0.0f;
    #pragma unroll
    for (int i = 0; i < 4; i++) { float d = vals[i] - mean; v += d * d; }
    #pragma unroll
    for (int off = 32; off >= 1; off >>= 1) v += __shfl_xor(v, off, 64);
    if (lane == 0) red[4 + wid] = v;
    __syncthreads();
    const float var  = (red[4] + red[5] + red[6] + red[7]) * (1.0f / Hq);
    const float rstd = rsqrtf(var + 1e-12f);

    float4 gm = *(const float4*)(gamma + c0);
    float4 bt = *(const float4*)(beta + c0);
    float4 o;
    o.x = (vals[0] - mean) * rstd * gm.x + bt.x;
    o.y = (vals[1] - mean) * rstd * gm.y + bt.y;
    o.z = (vals[2] - mean) * rstd * gm.z + bt.z;
    o.w = (vals[3] - mean) * rstd * gm.w + bt.w;
    *(float4*)(out + (size_t)row * Hq + c0) = o;
}

// ---------------------------------------------------------------------------
extern "C" void kernel_launch(void* const* d_in, const int* in_sizes, int n_in,
                              void* d_out, int out_size, void* d_ws, size_t ws_size,
                              hipStream_t stream)
{
    const float* hidden = (const float*)d_in[0];
    const float* mask   = (const float*)d_in[1];
    const float* W_qkv  = (const float*)d_in[2];
    const float* b_qkv  = (const float*)d_in[3];
    const float* W_out  = (const float*)d_in[4];
    const float* b_out  = (const float*)d_in[5];
    const float* gamma  = (const float*)d_in[6];
    const float* beta   = (const float*)d_in[7];
    float* out = (float*)d_out;

    const size_t nHid  = (size_t)Mq * Hq;        // 4 M
    const size_t nWq   = (size_t)H3q * Hq;       // 3 M
    const size_t nWo   = (size_t)Hq * Hq;        // 1 M
    const size_t nCtx  = (size_t)Mq * Hq;        // 4 M

    unsigned short* hidden_bf = (unsigned short*)d_ws;
    unsigned short* Wqkv_bf   = hidden_bf + nHid;
    unsigned short* Wout_bf   = Wqkv_bf + nWq;
    unsigned short* qb        = Wout_bf + nWo;          // Q  [4096][1024]
    unsigned short* kd        = qb + nHid;              // K  [4096][1024]
    unsigned short* v5        = kd + nHid;              // V' fragment-packed, 4 M
    unsigned short* ctx_bf    = v5 + nHid;
    unsigned short* x_bf      = ctx_bf + nCtx;
    unsigned short* opart     = x_bf + nHid;            // 2 * 4M bf16 = 16 MB
    float*          lpart     = (float*)(opart + 2 * nHid);  // 2*64K floats
    unsigned short* em2       = (unsigned short*)(lpart + 2 * (size_t)Mq * Nq);

    dim3 blk(256);

    // 0) fused fp32 -> bf16 cast + permuted expmask table
    cvt_all<<<dim3((int)(N_ALL / 2048)), blk, 0, stream>>>(
        hidden, W_qkv, W_out, hidden_bf);
    cvt_mask<<<dim3(2), blk, 0, stream>>>(mask, em2);

    // 1) QKV projection (MFMA) -> Qb / Kd / V5 (e^mask folded into V')
    gemm_mfma_qkv<<<dim3(H3q / TN, Mq / TM), blk, 0, stream>>>(
        hidden_bf, Wqkv_bf, b_qkv, mask, qb, kd, v5, Hq);

    // 2) Pipelined grid-split-K MFMA flash attention -> partial O/l
    attn_mfma<<<dim3(Sq / 128, Bq * Nq, 2), blk, 0, stream>>>(
        qb, kd, v5, em2, opart, lpart);

    // 2b) merge halves -> ctx bf16
    attn_merge<<<dim3((int)(nCtx / 1024)), blk, 0, stream>>>(
        opart, lpart, ctx_bf);

    // 3) Output projection (MFMA) + bias + residual -> x bf16
    gemm_mfma_out<<<dim3(Hq / TN, Mq / TM), blk, 0, stream>>>(
        ctx_bf, Wout_bf, b_out, hidden, x_bf, Mq, Hq, Hq);

    // 4) LayerNorm: bf16 x -> fp32 out
    ln_kernel<<<dim3(Mq), blk, 0, stream>>>(x_bf, gamma, beta, out);
}